// Round 1
// baseline (676.095 us; speedup 1.0000x reference)
//
#include <hip/hip_runtime.h>
#include <math.h>

#define BATCH 16384
#define NCLS  8192
#define NTAIL 16

// ws layout: [0, BATCH*4)            p_true  (float[BATCH])
//            [BATCH*4, BATCH*4+64)   tail counts (int[NTAIL])

__global__ void init_kernel(float* __restrict__ out, int* __restrict__ counts) {
    int t = threadIdx.x;
    if (t < NTAIL) counts[t] = 0;
    if (t == 0)    out[0] = 0.0f;
}

// One block (256 threads = 4 waves) per row. Single pass: online softmax
// (running max m, rescaled sum s) fused with argmax tracking.
__global__ __launch_bounds__(256) void row_kernel(const float* __restrict__ x,
                                                  const int* __restrict__ labels,
                                                  float* __restrict__ p_true,
                                                  int* __restrict__ counts) {
    const int row = blockIdx.x;
    const int t   = threadIdx.x;
    const float4* rowp = (const float4*)(x + (size_t)row * NCLS);

    float m = -INFINITY, s = 0.0f;
    int   idx = 0;
    #pragma unroll
    for (int k = 0; k < NCLS / (256 * 4); ++k) {
        float4 v = rowp[t + k * 256];
        const int c0 = (t + k * 256) * 4;
        float e[4] = {v.x, v.y, v.z, v.w};
        #pragma unroll
        for (int j = 0; j < 4; ++j) {
            float xv = e[j];
            xv = (xv == xv) ? xv : 0.0f;          // nan_to_num
            if (xv > m) {                          // strict > => first-occurrence argmax
                s = s * __expf(m - xv) + 1.0f;     // exp(-inf)=0 bootstraps cleanly
                m = xv; idx = c0 + j;
            } else {
                s += __expf(xv - m);
            }
        }
    }

    // wave(64)-level reduce of (m, idx, s)
    #pragma unroll
    for (int off = 32; off; off >>= 1) {
        float m2 = __shfl_down(m, off);
        float s2 = __shfl_down(s, off);
        int   i2 = __shfl_down(idx, off);
        if (m2 > m)       { s = s * __expf(m - m2) + s2; m = m2; idx = i2; }
        else if (m2 == m) { s += s2; idx = min(idx, i2); }
        else              { s += s2 * __expf(m2 - m); }
    }

    __shared__ float sm[4], ss[4];
    __shared__ int   si[4];
    const int wave = t >> 6;
    if ((t & 63) == 0) { sm[wave] = m; ss[wave] = s; si[wave] = idx; }
    __syncthreads();

    if (t == 0) {
        for (int wgi = 1; wgi < 4; ++wgi) {
            float m2 = sm[wgi], s2 = ss[wgi]; int i2 = si[wgi];
            if (m2 > m)       { s = s * __expf(m - m2) + s2; m = m2; idx = i2; }
            else if (m2 == m) { s += s2; idx = min(idx, i2); }
            else              { s += s2 * __expf(m2 - m); }
        }
        const int lab = labels[row];
        float xt = x[(size_t)row * NCLS + lab];
        xt = (xt == xt) ? xt : 0.0f;
        p_true[row] = __expf(xt - m) / s;
        if (idx >= NCLS - NTAIL) atomicAdd(&counts[idx - (NCLS - NTAIL)], 1);
    }
}

__global__ __launch_bounds__(256) void penalty_kernel(const float* __restrict__ p_true,
                                                      const int* __restrict__ labels,
                                                      const int* __restrict__ prev_counts,
                                                      const int* __restrict__ counts,
                                                      float* __restrict__ out) {
    const int i = blockIdx.x * 256 + threadIdx.x;
    const float p = p_true[i];
    const int lab = labels[i];
    float w = 1.0f;
    if (lab >= NCLS - NTAIL) {
        const int prev = prev_counts[lab];
        const int curr = counts[lab - (NCLS - NTAIL)];
        w = (prev > 0 && curr < prev) ? 4.0f
          : (prev > 0 && curr > prev) ? 2.0f
          : 3.0f;
    }
    float pen = -logf(p + 1e-7f) * (1.0f - p) * w;

    #pragma unroll
    for (int off = 32; off; off >>= 1) pen += __shfl_down(pen, off);

    __shared__ float acc[4];
    if ((threadIdx.x & 63) == 0) acc[threadIdx.x >> 6] = pen;
    __syncthreads();
    if (threadIdx.x == 0) {
        const float bs = acc[0] + acc[1] + acc[2] + acc[3];
        atomicAdd(out, bs * (0.1f / (float)BATCH));
    }
}

extern "C" void kernel_launch(void* const* d_in, const int* in_sizes, int n_in,
                              void* d_out, int out_size, void* d_ws, size_t ws_size,
                              hipStream_t stream) {
    const float* x           = (const float*)d_in[0];
    const int*   labels      = (const int*)  d_in[1];
    const int*   prev_counts = (const int*)  d_in[2];
    // d_in[3] (tail_mask) is deterministic: class >= NCLS-NTAIL — recomputed inline.

    float* out    = (float*)d_out;
    float* p_true = (float*)d_ws;
    int*   counts = (int*)((char*)d_ws + BATCH * sizeof(float));

    init_kernel<<<1, 64, 0, stream>>>(out, counts);
    row_kernel<<<BATCH, 256, 0, stream>>>(x, labels, p_true, counts);
    penalty_kernel<<<BATCH / 256, 256, 0, stream>>>(p_true, labels, prev_counts, counts, out);
}